// Round 8
// baseline (5048.941 us; speedup 1.0000x reference)
//
#include <hip/hip_runtime.h>

// LSTM autoencoder, fused single kernel. B=256 blocks (1/CU), 640 thr (10 waves).
// Role separation so NO lane exceeds ~125 VGPRs (rounds 4/6/7 showed the
// allocator caps at 128 and spills ~40 dwords -> 21MB scratch WRITE + per-step
// L2 reloads on the critical path):
//   e-loop: e1 on waves 0-7 (64 units x 8 k-slices, 48 wdwords/lane),
//           e2 on wave 8, x-prefetch (depth 2) on wave 9.
//   d-loop: d2 on waves 0-7 (128 units x 4 k-slices, 96 wdwords/lane),
//           d1 on waves 8-9 (64 units x 2 k-halves, 64 wdwords/lane).
// Reduce via DPP only: xor1(0xB1), xor2(0x4E), row_half_mirror(0x141).
// Quad-split activation (2 transcendentals/lane) for e1/e2/d2; d1 full.
// f16x2 weights in regs + v_dot2_f32_f16 (f32 accum). One barrier/step.

#define BB 256
#define TT 512

typedef _Float16 half2v __attribute__((ext_vector_type(2)));

static __device__ __forceinline__ float sigm(float v){ return 1.0f/(1.0f+__expf(-v)); }
static __device__ __forceinline__ float tanh_(float v){ return 1.0f - 2.0f/(__expf(2.0f*v)+1.0f); }
static __device__ __forceinline__ float dot2(half2v a, half2v b, float c){
  return __builtin_amdgcn_fdot2(a,b,c,false);
}
template<int CTRL>
static __device__ __forceinline__ float qb(float v){
  return __int_as_float(__builtin_amdgcn_update_dpp(0, __float_as_int(v), CTRL, 0xF, 0xF, true));
}
static __device__ __forceinline__ float qsum1(float v){ return v + qb<0xB1>(v); }
static __device__ __forceinline__ float qsum2(float v){ return v + qb<0x4E>(v); }
static __device__ __forceinline__ float hsum8(float v){        // sum over 8-lane group
  v = qsum1(v); v = qsum2(v); return v + qb<0x141>(v);         // 0x141 = row_half_mirror (l^7)
}
static __device__ __forceinline__ unsigned packh2(float lo, float hi){
  half2v p; p.x=(_Float16)lo; p.y=(_Float16)hi;
  return __builtin_bit_cast(unsigned, p);
}
static __device__ __forceinline__ half2v ash2(unsigned u){ return __builtin_bit_cast(half2v,u); }
static __device__ __forceinline__ half2v mkh2(float lo, float hi){
  half2v p; p.x=(_Float16)lo; p.y=(_Float16)hi; return p;
}

// Quad lanes hold identical a0..a3=(i,f,g,o). Lane q activates gate q (tanh
// via 2*sigm(2v)-1), DPP quad-broadcasts, updates c, returns h. (Proven r7.)
static __device__ __forceinline__ float lstm_update(int q, float a0, float a1,
                                                    float a2, float a3, float& c){
  float mine = a0;
  mine = (q==1) ? a1 : mine;
  mine = (q==2) ? a2 : mine;
  mine = (q==3) ? a3 : mine;
  const bool isg = (q==2);
  const float arg = isg ? (mine+mine) : mine;
  const float s   = 1.0f/(1.0f + __expf(-arg));
  const float act = isg ? (s+s-1.0f) : s;
  const float bi = qb<0x00>(act);
  const float bf = qb<0x55>(act);
  const float bg = qb<0xAA>(act);
  const float bo = qb<0xFF>(act);
  c = bf*c + bi*bg;
  const float s2 = 1.0f/(1.0f + __expf(-(c+c)));
  return bo*(s2+s2-1.0f);
}

__global__ void __launch_bounds__(640) k_fused(
    const float* __restrict__ x,
    const float* __restrict__ WihE1, const float* __restrict__ WhhE1,
    const float* __restrict__ bihE1, const float* __restrict__ bhhE1,
    const float* __restrict__ WihE2, const float* __restrict__ WhhE2,
    const float* __restrict__ bihE2, const float* __restrict__ bhhE2,
    const float* __restrict__ WihD1, const float* __restrict__ WhhD1,
    const float* __restrict__ bihD1, const float* __restrict__ bhhD1,
    const float* __restrict__ WihD2, const float* __restrict__ WhhD2,
    const float* __restrict__ bihD2, const float* __restrict__ bhhD2,
    float* __restrict__ out)
{
  const int b = blockIdx.x, tid = threadIdx.x;

  __shared__ unsigned vhE [2*96];  // e1 operand: x(t) 64dw || h1(t-1) 32dw (f16)
  __shared__ unsigned e2op[2*48];  // e2 operand: relu(h1) 32dw || h2 8dw || pad 8dw
  __shared__ unsigned dop [2*96];  // d2 operand: relu(hd1) 32dw || hd2 64dw
  __shared__ unsigned vhD1[2*32];  // d1 h-state (f16)
  __shared__ float    latF[16];

  //======================= ENCODER =======================
  {
    // e1: waves 0-7. unit j in [0,64), slice o in [0,8). K=192 -> 24 f16/slice.
    const bool e1act = (tid < 512);
    const int o = tid & 7, j = tid >> 3;
    half2v w1[4][12];
    float bias1[4] = {0.f,0.f,0.f,0.f};
    if (e1act){
#pragma unroll
      for (int g=0; g<4; ++g){
        const int row = g*64 + j;
        bias1[g] = (o==0) ? (bihE1[row]+bhhE1[row]) : 0.0f;
#pragma unroll
        for (int m=0;m<12;++m){
          const int k0 = 24*o + 2*m;            // concat {x:128, h:64}, k0 even
          const float lo = (k0   < 128)? WihE1[row*128+k0]   : WhhE1[row*64 + (k0-128)];
          const float hi = (k0+1 < 128)? WihE1[row*128+k0+1] : WhhE1[row*64 + (k0+1-128)];
          w1[g][m] = mkh2(lo,hi);
        }
      }
    }
    // e2: wave 8 (tid 512..575), unit j2 in [0,16), K=96 padded {h1:64,h2:16,pad:16}
    const bool e2act = (tid >= 512 && tid < 576);
    const int q2 = tid & 3, j2 = (tid - 512) >> 2;
    half2v w2[4][12];
    float bias2[4] = {0.f,0.f,0.f,0.f};
    if (e2act){
#pragma unroll
      for (int g=0; g<4; ++g){
        const int row = g*16 + j2;
        bias2[g] = (q2==0) ? (bihE2[row]+bhhE2[row]) : 0.0f;
#pragma unroll
        for (int m=0;m<12;++m){
          const int k0 = 24*q2 + 2*m;
          float lo = 0.0f, hi = 0.0f;
          if (k0 < 64)        lo = WihE2[row*64+k0];
          else if (k0 < 80)   lo = WhhE2[row*16 + (k0-64)];
          if (k0+1 < 64)      hi = WihE2[row*64+k0+1];
          else if (k0+1 < 80) hi = WhhE2[row*16 + (k0+1-64)];
          w2[g][m] = mkh2(lo,hi);
        }
      }
    }
    // x staging: wave 9 (tid 576..639), depth-2 prefetch
    const bool xact = (tid >= 576);
    const int  xl   = tid - 576;
    const float* xrow = x + (size_t)b * (TT*128);
    float2 xa, xb;
    if (xact){
      float2 v0 = *(const float2*)(xrow + 2*xl);
      vhE[xl] = packh2(v0.x, v0.y);             // x(0) -> parity 0
      xa = *(const float2*)(xrow + 1*128 + 2*xl);
      xb = *(const float2*)(xrow + 2*128 + 2*xl);
    }
    if (tid >= 64 && tid < 96)   vhE[tid] = 0u;      // h1(-1)=0 (parity 0)
    if (tid >= 96 && tid < 192)  e2op[tid-96] = 0u;  // h2(-1)+pads=0 (both parities)
    float c1 = 0.0f, c2 = 0.0f;
    __syncthreads();

    for (int t = 0; t <= TT; ++t){
      const int cur = t & 1, nxt = cur ^ 1;
      // ----- e1 step t (waves 0-7)
      if (t < TT && e1act){
        float a0=bias1[0], a1=bias1[1], a2=bias1[2], a3=bias1[3];
        const uint4* vp = (const uint4*)(vhE + cur*96 + o*12);
#pragma unroll
        for (int r=0;r<3;++r){
          const uint4 u = vp[r];
          const half2v o0=ash2(u.x), o1=ash2(u.y), o2=ash2(u.z), o3=ash2(u.w);
          a0=dot2(w1[0][4*r+0],o0,a0); a1=dot2(w1[1][4*r+0],o0,a1);
          a2=dot2(w1[2][4*r+0],o0,a2); a3=dot2(w1[3][4*r+0],o0,a3);
          a0=dot2(w1[0][4*r+1],o1,a0); a1=dot2(w1[1][4*r+1],o1,a1);
          a2=dot2(w1[2][4*r+1],o1,a2); a3=dot2(w1[3][4*r+1],o1,a3);
          a0=dot2(w1[0][4*r+2],o2,a0); a1=dot2(w1[1][4*r+2],o2,a1);
          a2=dot2(w1[2][4*r+2],o2,a2); a3=dot2(w1[3][4*r+2],o2,a3);
          a0=dot2(w1[0][4*r+3],o3,a0); a1=dot2(w1[1][4*r+3],o3,a1);
          a2=dot2(w1[2][4*r+3],o3,a2); a3=dot2(w1[3][4*r+3],o3,a3);
        }
        a0=hsum8(a0); a1=hsum8(a1); a2=hsum8(a2); a3=hsum8(a3);
        const float h = lstm_update(o & 3, a0, a1, a2, a3, c1);
        if (o == 0){
          ((_Float16*)(vhE + nxt*96))[128 + j] = (_Float16)h;
          ((_Float16*)(e2op + cur*48))[j]      = (_Float16)fmaxf(h, 0.0f);
        }
      }
      // ----- x stage x(t+1) (wave 9)
      if (t < TT && xact){
        vhE[nxt*96 + xl] = packh2(xa.x, xa.y);
        xa = xb;
        const int t3 = (t+3 < TT) ? (t+3) : (TT-1);
        xb = *(const float2*)(xrow + (size_t)t3*128 + 2*xl);
      }
      // ----- e2 step t2 = t-1 (wave 8)
      if (t >= 1 && e2act){
        const int t2 = t-1, c2p = t2 & 1, n2p = c2p ^ 1;
        float a0=bias2[0], a1=bias2[1], a2=bias2[2], a3=bias2[3];
        const uint4* vp = (const uint4*)(e2op + c2p*48 + q2*12);
#pragma unroll
        for (int r=0;r<3;++r){
          const uint4 u = vp[r];
          const half2v o0=ash2(u.x), o1=ash2(u.y), o2=ash2(u.z), o3=ash2(u.w);
          a0=dot2(w2[0][4*r+0],o0,a0); a1=dot2(w2[1][4*r+0],o0,a1);
          a2=dot2(w2[2][4*r+0],o0,a2); a3=dot2(w2[3][4*r+0],o0,a3);
          a0=dot2(w2[0][4*r+1],o1,a0); a1=dot2(w2[1][4*r+1],o1,a1);
          a2=dot2(w2[2][4*r+1],o1,a2); a3=dot2(w2[3][4*r+1],o1,a3);
          a0=dot2(w2[0][4*r+2],o2,a0); a1=dot2(w2[1][4*r+2],o2,a1);
          a2=dot2(w2[2][4*r+2],o2,a2); a3=dot2(w2[3][4*r+2],o2,a3);
          a0=dot2(w2[0][4*r+3],o3,a0); a1=dot2(w2[1][4*r+3],o3,a1);
          a2=dot2(w2[2][4*r+3],o3,a2); a3=dot2(w2[3][4*r+3],o3,a3);
        }
        a0=qsum2(qsum1(a0)); a1=qsum2(qsum1(a1));
        a2=qsum2(qsum1(a2)); a3=qsum2(qsum1(a3));
        const float h = lstm_update(q2, a0, a1, a2, a3, c2);
        if (q2 == 0){
          ((_Float16*)(e2op + n2p*48))[64 + j2] = (_Float16)h;
          if (t2 == TT-1) latF[j2] = fmaxf(h, 0.0f);
        }
      }
      __syncthreads();
    }
  }
  __syncthreads();

  //======================= DECODER =======================
  {
    // d2: waves 0-7 (as round 7). unit jd in [0,128), slice qd in [0,4).
    const bool d2act = (tid < 512);
    const int qd = tid & 3, jd = tid >> 2;
    half2v wD2[4][24];
    float biasD2[4] = {0.f,0.f,0.f,0.f};
    if (d2act){
#pragma unroll
      for (int g=0; g<4; ++g){
        const int row = g*128 + jd;
        biasD2[g] = (qd==0)? (bihD2[row]+bhhD2[row]) : 0.0f;
#pragma unroll
        for (int m=0;m<24;++m){
          const int k0 = 48*qd + 2*m;           // concat {x:64, h:128}
          const float lo = (k0   < 64)? WihD2[row*64+k0]   : WhhD2[row*128+(k0-64)];
          const float hi = (k0+1 < 64)? WihD2[row*64+k0+1] : WhhD2[row*128+(k0+1-64)];
          wD2[g][m] = mkh2(lo,hi);
        }
      }
    }
    // d1: waves 8-9 (tid 512..639). unit du in [0,64), k-half dsl in {0,1}.
    const bool d1act = (tid >= 512);
    const int di = tid - 512, du = di >> 1, dsl = di & 1;
    half2v wD1[4][16];
    float projD1[4] = {0.f,0.f,0.f,0.f};
    if (d1act){
#pragma unroll
      for (int g=0; g<4; ++g){
        const int row = g*64 + du;
#pragma unroll
        for (int m=0;m<16;++m){
          const int k0 = dsl*32 + 2*m;          // h only, K=64
          wD1[g][m] = mkh2(WhhD1[row*64+k0], WhhD1[row*64+k0+1]);
        }
        if (dsl==0){
          float a = bihD1[row]+bhhD1[row];
#pragma unroll
          for (int i=0;i<16;++i) a = fmaf(WihD1[row*16+i], latF[i], a);
          projD1[g] = a;
        }
      }
    }
    if (tid < 192)               dop[tid] = 0u;        // hd2(-1)=0 (both parities)
    if (tid >= 192 && tid < 224) vhD1[tid-192] = 0u;   // hd1(-1)=0 (parity 0)
    float cd1 = 0.0f, cd2 = 0.0f;
    float* orow = out + (size_t)b * (TT*128);
    __syncthreads();

    for (int t = 0; t <= TT; ++t){
      const int cur = t & 1;
      // ----- d1 step t (waves 8-9, leads d2 by 1)
      if (t < TT && d1act){
        const int nxt = cur ^ 1;
        float a0=projD1[0], a1=projD1[1], a2=projD1[2], a3=projD1[3];
        const uint4* vp = (const uint4*)(vhD1 + cur*32 + dsl*16);
#pragma unroll
        for (int r=0;r<4;++r){
          const uint4 u = vp[r];
          const half2v o0=ash2(u.x),o1=ash2(u.y),o2=ash2(u.z),o3=ash2(u.w);
          a0=dot2(wD1[0][4*r+0],o0,a0); a1=dot2(wD1[1][4*r+0],o0,a1);
          a2=dot2(wD1[2][4*r+0],o0,a2); a3=dot2(wD1[3][4*r+0],o0,a3);
          a0=dot2(wD1[0][4*r+1],o1,a0); a1=dot2(wD1[1][4*r+1],o1,a1);
          a2=dot2(wD1[2][4*r+1],o1,a2); a3=dot2(wD1[3][4*r+1],o1,a3);
          a0=dot2(wD1[0][4*r+2],o2,a0); a1=dot2(wD1[1][4*r+2],o2,a1);
          a2=dot2(wD1[2][4*r+2],o2,a2); a3=dot2(wD1[3][4*r+2],o2,a3);
          a0=dot2(wD1[0][4*r+3],o3,a0); a1=dot2(wD1[1][4*r+3],o3,a1);
          a2=dot2(wD1[2][4*r+3],o3,a2); a3=dot2(wD1[3][4*r+3],o3,a3);
        }
        a0=qsum1(a0); a1=qsum1(a1); a2=qsum1(a2); a3=qsum1(a3);
        const float i_=sigm(a0), f_=sigm(a1), g_=tanh_(a2), o_=sigm(a3);
        cd1 = f_*cd1 + i_*g_;
        const float h = o_*tanh_(cd1);
        if (dsl==0){
          ((_Float16*)(vhD1 + nxt*32))[du] = (_Float16)h;
          ((_Float16*)(dop + cur*96))[du]  = (_Float16)fmaxf(h,0.0f);
        }
      }
      // ----- d2 step t2 = t-1 (waves 0-7)
      if (t >= 1 && d2act){
        const int t2 = t-1, c2p = t2 & 1, n2p = c2p ^ 1;
        float a0=biasD2[0], a1=biasD2[1], a2=biasD2[2], a3=biasD2[3];
        const uint4* vp = (const uint4*)(dop + c2p*96 + qd*24);
#pragma unroll
        for (int r=0;r<6;++r){
          const uint4 u = vp[r];
          const half2v o0=ash2(u.x),o1=ash2(u.y),o2=ash2(u.z),o3=ash2(u.w);
          a0=dot2(wD2[0][4*r+0],o0,a0); a1=dot2(wD2[1][4*r+0],o0,a1);
          a2=dot2(wD2[2][4*r+0],o0,a2); a3=dot2(wD2[3][4*r+0],o0,a3);
          a0=dot2(wD2[0][4*r+1],o1,a0); a1=dot2(wD2[1][4*r+1],o1,a1);
          a2=dot2(wD2[2][4*r+1],o1,a2); a3=dot2(wD2[3][4*r+1],o1,a3);
          a0=dot2(wD2[0][4*r+2],o2,a0); a1=dot2(wD2[1][4*r+2],o2,a1);
          a2=dot2(wD2[2][4*r+2],o2,a2); a3=dot2(wD2[3][4*r+2],o2,a3);
          a0=dot2(wD2[0][4*r+3],o3,a0); a1=dot2(wD2[1][4*r+3],o3,a1);
          a2=dot2(wD2[2][4*r+3],o3,a2); a3=dot2(wD2[3][4*r+3],o3,a3);
        }
        a0=qsum2(qsum1(a0)); a1=qsum2(qsum1(a1));
        a2=qsum2(qsum1(a2)); a3=qsum2(qsum1(a3));
        const float h = lstm_update(qd, a0, a1, a2, a3, cd2);
        if (qd==0){
          ((_Float16*)(dop + n2p*96))[64 + jd] = (_Float16)h;
          orow[(size_t)t2*128 + jd] = h;
        }
      }
      __syncthreads();
    }
  }
}

extern "C" void kernel_launch(void* const* d_in, const int* in_sizes, int n_in,
                              void* d_out, int out_size, void* d_ws, size_t ws_size,
                              hipStream_t stream) {
  const float* x      = (const float*)d_in[0];
  const float* WihE1  = (const float*)d_in[1];
  const float* WhhE1  = (const float*)d_in[2];
  const float* bihE1  = (const float*)d_in[3];
  const float* bhhE1  = (const float*)d_in[4];
  const float* WihE2  = (const float*)d_in[5];
  const float* WhhE2  = (const float*)d_in[6];
  const float* bihE2  = (const float*)d_in[7];
  const float* bhhE2  = (const float*)d_in[8];
  const float* WihD1  = (const float*)d_in[9];
  const float* WhhD1  = (const float*)d_in[10];
  const float* bihD1  = (const float*)d_in[11];
  const float* bhhD1  = (const float*)d_in[12];
  const float* WihD2  = (const float*)d_in[13];
  const float* WhhD2  = (const float*)d_in[14];
  const float* bihD2  = (const float*)d_in[15];
  const float* bhhD2  = (const float*)d_in[16];
  float* out = (float*)d_out;

  k_fused<<<BB, 640, 0, stream>>>(x,
      WihE1, WhhE1, bihE1, bhhE1,
      WihE2, WhhE2, bihE2, bhhE2,
      WihD1, WhhD1, bihD1, bhhD1,
      WihD2, WhhD2, bihD2, bhhD2,
      out);
}

// Round 9
// 995.944 us; speedup vs baseline: 5.0695x; 5.0695x over previous
//
#include <hip/hip_runtime.h>

// LSTM autoencoder, fused, PHASE-SEQUENTIAL single kernel. 256 blocks, 512 thr.
// Allocator lesson (r4-r8): budget is 128 VGPR at 512thr (84 at 640thr!);
// min-waves hint does not raise it; >~115 dwords/lane anywhere => global spill.
// So: three sequential phases, each's weight set dead afterward, each <=~110:
//   A: e1 (all lanes, Q=8 k-split, 48dw) || e2 lag-1 (wave1, +28dw) || x-stage (wave0)
//   B: d1 alone (lanes<256, Q=4, 36dw)
//   C: d2 alone (all lanes, Q=4, 96dw -- r5 measured 108 VGPR standalone)
// Full-sequence intermediate hbuf[512][64 f16] = 64KB LDS (of 160KB): relu(h1)
// then relu(hd1) -- intermediates NEVER touch HBM. e2/d2 operands assembled via
// per-read address-select hbuf vs small ring (r6-proven). DPP-only reduces,
// quad-split activation (r7/r8-proven). One barrier/step.

#define BB 256
#define TT 512

typedef _Float16 half2v __attribute__((ext_vector_type(2)));

static __device__ __forceinline__ float dot2(half2v a, half2v b, float c){
  return __builtin_amdgcn_fdot2(a,b,c,false);
}
template<int CTRL>
static __device__ __forceinline__ float qb(float v){
  return __int_as_float(__builtin_amdgcn_update_dpp(0, __float_as_int(v), CTRL, 0xF, 0xF, true));
}
static __device__ __forceinline__ float qsum1(float v){ return v + qb<0xB1>(v); }
static __device__ __forceinline__ float qsum2(float v){ return v + qb<0x4E>(v); }
static __device__ __forceinline__ float hsum8(float v){       // 8-lane-group sum
  v = qsum1(v); v = qsum2(v); return v + qb<0x141>(v);        // row_half_mirror
}
static __device__ __forceinline__ unsigned packh2(float lo, float hi){
  half2v p; p.x=(_Float16)lo; p.y=(_Float16)hi;
  return __builtin_bit_cast(unsigned, p);
}
static __device__ __forceinline__ half2v ash2(unsigned u){ return __builtin_bit_cast(half2v,u); }
static __device__ __forceinline__ half2v mkh2(float lo, float hi){
  half2v p; p.x=(_Float16)lo; p.y=(_Float16)hi; return p;
}

// Quad lanes hold identical a0..a3=(i,f,g,o). Lane q activates gate q (tanh
// via 2*sigm(2v)-1), DPP quad-broadcast, update c, return h. (r7/r8-proven.)
static __device__ __forceinline__ float lstm_update(int q, float a0, float a1,
                                                    float a2, float a3, float& c){
  float mine = a0;
  mine = (q==1) ? a1 : mine;
  mine = (q==2) ? a2 : mine;
  mine = (q==3) ? a3 : mine;
  const bool isg = (q==2);
  const float arg = isg ? (mine+mine) : mine;
  const float s   = 1.0f/(1.0f + __expf(-arg));
  const float act = isg ? (s+s-1.0f) : s;
  const float bi = qb<0x00>(act);
  const float bf = qb<0x55>(act);
  const float bg = qb<0xAA>(act);
  const float bo = qb<0xFF>(act);
  c = bf*c + bi*bg;
  const float s2 = 1.0f/(1.0f + __expf(-(c+c)));
  return bo*(s2+s2-1.0f);
}

__global__ void __launch_bounds__(512, 2) k_fused(
    const float* __restrict__ x,
    const float* __restrict__ WihE1, const float* __restrict__ WhhE1,
    const float* __restrict__ bihE1, const float* __restrict__ bhhE1,
    const float* __restrict__ WihE2, const float* __restrict__ WhhE2,
    const float* __restrict__ bihE2, const float* __restrict__ bhhE2,
    const float* __restrict__ WihD1, const float* __restrict__ WhhD1,
    const float* __restrict__ bihD1, const float* __restrict__ bhhD1,
    const float* __restrict__ WihD2, const float* __restrict__ WhhD2,
    const float* __restrict__ bihD2, const float* __restrict__ bhhD2,
    float* __restrict__ out)
{
  const int b = blockIdx.x, tid = threadIdx.x;

  __shared__ unsigned hbuf[TT*32];  // [t][32dw]: 64 f16 — relu(h1), then relu(hd1). 64KB
  __shared__ unsigned vhE [2*96];   // e1 operand ring: x 64dw || h1 32dw (f16)
  __shared__ unsigned h2r [2*16];   // e2 h2 ring: h2 8dw || zero-pad 8dw
  __shared__ unsigned vhD1[2*32];   // d1 h ring
  __shared__ unsigned drng[2*64];   // d2 h ring (128 f16)
  __shared__ float    latF[16];

  //================= PHASE A: e1 || e2(lag-1) || x-stage =================
  {
    const int o = tid & 7, j = tid >> 3;          // e1: all lanes, unit j, slice o
    half2v w1[4][12];
    float bias1[4];
#pragma unroll
    for (int g=0; g<4; ++g){
      const int row = g*64 + j;
      bias1[g] = (o==0) ? (bihE1[row]+bhhE1[row]) : 0.0f;
#pragma unroll
      for (int m=0;m<12;++m){
        const int k0 = 24*o + 2*m;                // concat {x:128, h:64}
        const float lo = (k0   < 128)? WihE1[row*128+k0]   : WhhE1[row*64 + (k0-128)];
        const float hi = (k0+1 < 128)? WihE1[row*128+k0+1] : WhhE1[row*64 + (k0+1-128)];
        w1[g][m] = mkh2(lo,hi);
      }
    }
    // e2: wave 1 (tid 64..127). unit j2 in [0,16), slice q2. K=96 {h1:64,h2:16,pad:16}
    const bool e2act = (tid >= 64 && tid < 128);
    const int q2 = tid & 3, j2 = (tid - 64) >> 2;
    half2v w2[4][12];
    float bias2[4] = {0.f,0.f,0.f,0.f};
    if (e2act){
#pragma unroll
      for (int g=0; g<4; ++g){
        const int row = g*16 + j2;
        bias2[g] = (q2==0) ? (bihE2[row]+bhhE2[row]) : 0.0f;
#pragma unroll
        for (int m=0;m<12;++m){
          const int k0 = 24*q2 + 2*m;
          float lo = 0.0f, hi = 0.0f;
          if (k0 < 64)        lo = WihE2[row*64+k0];
          else if (k0 < 80)   lo = WhhE2[row*16 + (k0-64)];
          if (k0+1 < 64)      hi = WihE2[row*64+k0+1];
          else if (k0+1 < 80) hi = WhhE2[row*16 + (k0+1-64)];
          w2[g][m] = mkh2(lo,hi);
        }
      }
    }
    // x staging: lanes 0..63 (they also compute e1), depth-2 register prefetch
    const bool xact = (tid < 64);
    const float* xrow = x + (size_t)b * (TT*128);
    float2 xa, xb;
    if (xact){
      float2 v0 = *(const float2*)(xrow + 2*tid);
      vhE[tid] = packh2(v0.x, v0.y);              // x(0) -> parity 0
      xa = *(const float2*)(xrow + 128 + 2*tid);
      xb = *(const float2*)(xrow + 256 + 2*tid);
    }
    if (tid >= 128 && tid < 160) vhE[64 + (tid-128)] = 0u;  // h1(-1)=0 (parity 0)
    if (tid >= 160 && tid < 192) h2r[tid-160] = 0u;         // h2(-1)+pads=0 (both par.)
    float c1 = 0.0f, c2 = 0.0f;
    __syncthreads();

    for (int t = 0; t <= TT; ++t){
      const int cur = t & 1, nxt = cur ^ 1;
      if (t < TT && xact){                        // stage x(t+1); refill depth-2
        vhE[nxt*96 + tid] = packh2(xa.x, xa.y);
        xa = xb;
        const int t3 = (t+3 < TT) ? (t+3) : (TT-1);
        xb = *(const float2*)(xrow + (size_t)t3*128 + 2*tid);
      }
      if (t < TT){                                // e1 step t
        float a0=bias1[0], a1=bias1[1], a2=bias1[2], a3=bias1[3];
        const uint4* vp = (const uint4*)(vhE + cur*96 + o*12);
#pragma unroll
        for (int r=0;r<3;++r){
          const uint4 u = vp[r];
          const half2v o0=ash2(u.x), o1=ash2(u.y), o2=ash2(u.z), o3=ash2(u.w);
          a0=dot2(w1[0][4*r+0],o0,a0); a1=dot2(w1[1][4*r+0],o0,a1);
          a2=dot2(w1[2][4*r+0],o0,a2); a3=dot2(w1[3][4*r+0],o0,a3);
          a0=dot2(w1[0][4*r+1],o1,a0); a1=dot2(w1[1][4*r+1],o1,a1);
          a2=dot2(w1[2][4*r+1],o1,a2); a3=dot2(w1[3][4*r+1],o1,a3);
          a0=dot2(w1[0][4*r+2],o2,a0); a1=dot2(w1[1][4*r+2],o2,a1);
          a2=dot2(w1[2][4*r+2],o2,a2); a3=dot2(w1[3][4*r+2],o2,a3);
          a0=dot2(w1[0][4*r+3],o3,a0); a1=dot2(w1[1][4*r+3],o3,a1);
          a2=dot2(w1[2][4*r+3],o3,a2); a3=dot2(w1[3][4*r+3],o3,a3);
        }
        a0=hsum8(a0); a1=hsum8(a1); a2=hsum8(a2); a3=hsum8(a3);
        const float h = lstm_update(o & 3, a0, a1, a2, a3, c1);
        if (o == 0){
          ((_Float16*)(vhE + nxt*96))[128 + j] = (_Float16)h;
          ((_Float16*)(hbuf + t*32))[j]        = (_Float16)fmaxf(h, 0.0f);
        }
      }
      if (t >= 1 && e2act){                       // e2 step t2 = t-1
        const int t2 = t-1, cp = t2 & 1, np = cp ^ 1;
        float a0=bias2[0], a1=bias2[1], a2=bias2[2], a3=bias2[3];
#pragma unroll
        for (int r=0;r<3;++r){
          const int d = q2*12 + 4*r;
          const unsigned* p = (d < 32) ? (hbuf + t2*32 + d) : (h2r + cp*16 + (d-32));
          const uint4 u = *(const uint4*)p;
          const half2v o0=ash2(u.x), o1=ash2(u.y), o2=ash2(u.z), o3=ash2(u.w);
          a0=dot2(w2[0][4*r+0],o0,a0); a1=dot2(w2[1][4*r+0],o0,a1);
          a2=dot2(w2[2][4*r+0],o0,a2); a3=dot2(w2[3][4*r+0],o0,a3);
          a0=dot2(w2[0][4*r+1],o1,a0); a1=dot2(w2[1][4*r+1],o1,a1);
          a2=dot2(w2[2][4*r+1],o1,a2); a3=dot2(w2[3][4*r+1],o1,a3);
          a0=dot2(w2[0][4*r+2],o2,a0); a1=dot2(w2[1][4*r+2],o2,a1);
          a2=dot2(w2[2][4*r+2],o2,a2); a3=dot2(w2[3][4*r+2],o2,a3);
          a0=dot2(w2[0][4*r+3],o3,a0); a1=dot2(w2[1][4*r+3],o3,a1);
          a2=dot2(w2[2][4*r+3],o3,a2); a3=dot2(w2[3][4*r+3],o3,a3);
        }
        a0=qsum2(qsum1(a0)); a1=qsum2(qsum1(a1));
        a2=qsum2(qsum1(a2)); a3=qsum2(qsum1(a3));
        const float h = lstm_update(q2, a0, a1, a2, a3, c2);
        if (q2 == 0){
          ((_Float16*)(h2r + np*16))[j2] = (_Float16)h;
          if (t2 == TT-1) latF[j2] = fmaxf(h, 0.0f);
        }
      }
      __syncthreads();
    }
  }
  __syncthreads();
  asm volatile("" ::: "memory");   // phase fence: A weights die here

  //================= PHASE B: d1 alone =================
  {
    const bool act = (tid < 256);                 // unit jd in [0,64), slice qd
    const int qd = tid & 3, jd = tid >> 2;
    half2v wD1[4][8];
    float projD1[4] = {0.f,0.f,0.f,0.f};
    if (act){
#pragma unroll
      for (int g=0; g<4; ++g){
        const int row = g*64 + jd;
#pragma unroll
        for (int m=0;m<8;++m){
          const int k0 = 16*qd + 2*m;             // h only, K=64
          wD1[g][m] = mkh2(WhhD1[row*64+k0], WhhD1[row*64+k0+1]);
        }
        if (qd==0){
          float a = bihD1[row]+bhhD1[row];
#pragma unroll
          for (int i=0;i<16;++i) a = fmaf(WihD1[row*16+i], latF[i], a);
          projD1[g] = a;
        }
      }
    }
    if (tid < 32) vhD1[tid] = 0u;                 // hd1(-1)=0 (parity 0)
    float cd1 = 0.0f;
    __syncthreads();

    for (int t = 0; t < TT; ++t){
      const int cur = t & 1, nxt = cur ^ 1;
      if (act){
        float a0=projD1[0], a1=projD1[1], a2=projD1[2], a3=projD1[3];
        const uint4* vp = (const uint4*)(vhD1 + cur*32 + qd*8);
#pragma unroll
        for (int r=0;r<2;++r){
          const uint4 u = vp[r];
          const half2v o0=ash2(u.x),o1=ash2(u.y),o2=ash2(u.z),o3=ash2(u.w);
          a0=dot2(wD1[0][4*r+0],o0,a0); a1=dot2(wD1[1][4*r+0],o0,a1);
          a2=dot2(wD1[2][4*r+0],o0,a2); a3=dot2(wD1[3][4*r+0],o0,a3);
          a0=dot2(wD1[0][4*r+1],o1,a0); a1=dot2(wD1[1][4*r+1],o1,a1);
          a2=dot2(wD1[2][4*r+1],o1,a2); a3=dot2(wD1[3][4*r+1],o1,a3);
          a0=dot2(wD1[0][4*r+2],o2,a0); a1=dot2(wD1[1][4*r+2],o2,a1);
          a2=dot2(wD1[2][4*r+2],o2,a2); a3=dot2(wD1[3][4*r+2],o2,a3);
          a0=dot2(wD1[0][4*r+3],o3,a0); a1=dot2(wD1[1][4*r+3],o3,a1);
          a2=dot2(wD1[2][4*r+3],o3,a2); a3=dot2(wD1[3][4*r+3],o3,a3);
        }
        a0=qsum2(qsum1(a0)); a1=qsum2(qsum1(a1));
        a2=qsum2(qsum1(a2)); a3=qsum2(qsum1(a3));
        const float h = lstm_update(qd, a0, a1, a2, a3, cd1);
        if (qd==0){
          ((_Float16*)(vhD1 + nxt*32))[jd] = (_Float16)h;
          ((_Float16*)(hbuf + t*32))[jd]   = (_Float16)fmaxf(h,0.0f);
        }
      }
      __syncthreads();
    }
  }
  __syncthreads();
  asm volatile("" ::: "memory");   // phase fence: B weights die here

  //================= PHASE C: d2 alone =================
  {
    const int qd = tid & 3, jd = tid >> 2;        // unit jd in [0,128), slice qd
    half2v wD2[4][24];
    float biasD2[4];
#pragma unroll
    for (int g=0; g<4; ++g){
      const int row = g*128 + jd;
      biasD2[g] = (qd==0)? (bihD2[row]+bhhD2[row]) : 0.0f;
#pragma unroll
      for (int m=0;m<24;++m){
        const int k0 = 48*qd + 2*m;               // concat {x:64, h:128}
        const float lo = (k0   < 64)? WihD2[row*64+k0]   : WhhD2[row*128+(k0-64)];
        const float hi = (k0+1 < 64)? WihD2[row*64+k0+1] : WhhD2[row*128+(k0+1-64)];
        wD2[g][m] = mkh2(lo,hi);
      }
    }
    if (tid < 64) drng[tid] = 0u;                 // hd2(-1)=0 (parity 0)
    float cd2 = 0.0f;
    float* orow = out + (size_t)b * (TT*128);
    __syncthreads();

    for (int t = 0; t < TT; ++t){
      const int cur = t & 1, nxt = cur ^ 1;
      float a0=biasD2[0], a1=biasD2[1], a2=biasD2[2], a3=biasD2[3];
#pragma unroll
      for (int r=0;r<6;++r){
        const int d = qd*24 + 4*r;
        const unsigned* p = (d < 32) ? (hbuf + t*32 + d) : (drng + cur*64 + (d-32));
        const uint4 u = *(const uint4*)p;
        const half2v o0=ash2(u.x),o1=ash2(u.y),o2=ash2(u.z),o3=ash2(u.w);
        a0=dot2(wD2[0][4*r+0],o0,a0); a1=dot2(wD2[1][4*r+0],o0,a1);
        a2=dot2(wD2[2][4*r+0],o0,a2); a3=dot2(wD2[3][4*r+0],o0,a3);
        a0=dot2(wD2[0][4*r+1],o1,a0); a1=dot2(wD2[1][4*r+1],o1,a1);
        a2=dot2(wD2[2][4*r+1],o1,a2); a3=dot2(wD2[3][4*r+1],o1,a3);
        a0=dot2(wD2[0][4*r+2],o2,a0); a1=dot2(wD2[1][4*r+2],o2,a1);
        a2=dot2(wD2[2][4*r+2],o2,a2); a3=dot2(wD2[3][4*r+2],o2,a3);
        a0=dot2(wD2[0][4*r+3],o3,a0); a1=dot2(wD2[1][4*r+3],o3,a1);
        a2=dot2(wD2[2][4*r+3],o3,a2); a3=dot2(wD2[3][4*r+3],o3,a3);
      }
      a0=qsum2(qsum1(a0)); a1=qsum2(qsum1(a1));
      a2=qsum2(qsum1(a2)); a3=qsum2(qsum1(a3));
      const float h = lstm_update(qd, a0, a1, a2, a3, cd2);
      if (qd==0){
        ((_Float16*)(drng + nxt*64))[jd] = (_Float16)h;
        orow[(size_t)t*128 + jd] = h;
      }
      __syncthreads();
    }
  }
}

extern "C" void kernel_launch(void* const* d_in, const int* in_sizes, int n_in,
                              void* d_out, int out_size, void* d_ws, size_t ws_size,
                              hipStream_t stream) {
  const float* x      = (const float*)d_in[0];
  const float* WihE1  = (const float*)d_in[1];
  const float* WhhE1  = (const float*)d_in[2];
  const float* bihE1  = (const float*)d_in[3];
  const float* bhhE1  = (const float*)d_in[4];
  const float* WihE2  = (const float*)d_in[5];
  const float* WhhE2  = (const float*)d_in[6];
  const float* bihE2  = (const float*)d_in[7];
  const float* bhhE2  = (const float*)d_in[8];
  const float* WihD1  = (const float*)d_in[9];
  const float* WhhD1  = (const float*)d_in[10];
  const float* bihD1  = (const float*)d_in[11];
  const float* bhhD1  = (const float*)d_in[12];
  const float* WihD2  = (const float*)d_in[13];
  const float* WhhD2  = (const float*)d_in[14];
  const float* bihD2  = (const float*)d_in[15];
  const float* bhhD2  = (const float*)d_in[16];
  float* out = (float*)d_out;

  k_fused<<<BB, 512, 0, stream>>>(x,
      WihE1, WhhE1, bihE1, bhhE1,
      WihE2, WhhE2, bihE2, bhhE2,
      WihD1, WhhD1, bihD1, bhhD1,
      WihD2, WhhD2, bihD2, bhhD2,
      out);
}

// Round 10
// 897.730 us; speedup vs baseline: 5.6241x; 1.1094x over previous
//
#include <hip/hip_runtime.h>

// LSTM autoencoder, fused, TWO-LOOP pipelined kernel. 256 blocks (1/CU), 512 thr.
// Register law (r4-r9 measured): budget 128 VGPR @512thr; >~115 dwords live
// anywhere => global spill (WRITE_SIZE tells the truth). r9 (phase-serial) is
// spill-free but pays 1536 barrier-steps. This round: 1026 steps.
//   e-loop (513): e1 all lanes (Q=8 k-split, 48dw regs)  || e2 lag-1 on wave 1
//                 || x depth-2 prefetch on lanes 0-63. (r9 phase A, ring ver.)
//   d-loop (513): d2 all lanes (Q=4, 96dw regs) || d1 lag-1 lead on lanes<256
//                 with weights in LDS (32KB, [r][lane][4dw] layout -> 8
//                 conflict-floor ds_read_b128/step) -> only ~12 extra regs.
// Contiguous 2-parity operand rings (r7-proven hazards): no per-read selects.
// DPP-only reduces; quad-split activation. One barrier/step.

#define BB 256
#define TT 512

typedef _Float16 half2v __attribute__((ext_vector_type(2)));

static __device__ __forceinline__ float dot2(half2v a, half2v b, float c){
  return __builtin_amdgcn_fdot2(a,b,c,false);
}
template<int CTRL>
static __device__ __forceinline__ float qb(float v){
  return __int_as_float(__builtin_amdgcn_update_dpp(0, __float_as_int(v), CTRL, 0xF, 0xF, true));
}
static __device__ __forceinline__ float qsum1(float v){ return v + qb<0xB1>(v); }
static __device__ __forceinline__ float qsum2(float v){ return v + qb<0x4E>(v); }
static __device__ __forceinline__ float hsum8(float v){       // 8-lane-group sum
  v = qsum1(v); v = qsum2(v); return v + qb<0x141>(v);        // row_half_mirror
}
static __device__ __forceinline__ unsigned packh2(float lo, float hi){
  half2v p; p.x=(_Float16)lo; p.y=(_Float16)hi;
  return __builtin_bit_cast(unsigned, p);
}
static __device__ __forceinline__ half2v ash2(unsigned u){ return __builtin_bit_cast(half2v,u); }
static __device__ __forceinline__ half2v mkh2(float lo, float hi){
  half2v p; p.x=(_Float16)lo; p.y=(_Float16)hi; return p;
}

// Quad lanes hold identical a0..a3=(i,f,g,o). Lane q activates gate q (tanh
// via 2*sigm(2v)-1), DPP quad-broadcast, update c, return h. (r7-r9 proven.)
static __device__ __forceinline__ float lstm_update(int q, float a0, float a1,
                                                    float a2, float a3, float& c){
  float mine = a0;
  mine = (q==1) ? a1 : mine;
  mine = (q==2) ? a2 : mine;
  mine = (q==3) ? a3 : mine;
  const bool isg = (q==2);
  const float arg = isg ? (mine+mine) : mine;
  const float s   = 1.0f/(1.0f + __expf(-arg));
  const float act = isg ? (s+s-1.0f) : s;
  const float bi = qb<0x00>(act);
  const float bf = qb<0x55>(act);
  const float bg = qb<0xAA>(act);
  const float bo = qb<0xFF>(act);
  c = bf*c + bi*bg;
  const float s2 = 1.0f/(1.0f + __expf(-(c+c)));
  return bo*(s2+s2-1.0f);
}

__global__ void __launch_bounds__(512, 2) k_fused(
    const float* __restrict__ x,
    const float* __restrict__ WihE1, const float* __restrict__ WhhE1,
    const float* __restrict__ bihE1, const float* __restrict__ bhhE1,
    const float* __restrict__ WihE2, const float* __restrict__ WhhE2,
    const float* __restrict__ bihE2, const float* __restrict__ bhhE2,
    const float* __restrict__ WihD1, const float* __restrict__ WhhD1,
    const float* __restrict__ bihD1, const float* __restrict__ bhhD1,
    const float* __restrict__ WihD2, const float* __restrict__ WhhD2,
    const float* __restrict__ bihD2, const float* __restrict__ bhhD2,
    float* __restrict__ out)
{
  const int b = blockIdx.x, tid = threadIdx.x;

  __shared__ unsigned wD1L[8*1024]; // 32KB d1 weights: [r 0..7][lane 0..255][4dw]
  __shared__ unsigned vhE [2*96];   // e1 operand ring: x 64dw || h1 32dw (f16)
  __shared__ unsigned e2op[2*48];   // e2 ring: relu(h1) 32dw || h2 8dw || pad0 8dw
  __shared__ unsigned dop [2*96];   // d2 ring: relu(hd1) 32dw || hd2 64dw
  __shared__ unsigned vhD1[2*32];   // d1 h ring
  __shared__ float    latF[16];

  //================= E-LOOP: e1 || e2(lag-1) || x-stage =================
  {
    const int o = tid & 7, j = tid >> 3;          // e1: all lanes, unit j, slice o
    half2v w1[4][12];
    float bias1[4];
#pragma unroll
    for (int g=0; g<4; ++g){
      const int row = g*64 + j;
      bias1[g] = (o==0) ? (bihE1[row]+bhhE1[row]) : 0.0f;
#pragma unroll
      for (int m=0;m<12;++m){
        const int k0 = 24*o + 2*m;                // concat {x:128, h:64}
        const float lo = (k0   < 128)? WihE1[row*128+k0]   : WhhE1[row*64 + (k0-128)];
        const float hi = (k0+1 < 128)? WihE1[row*128+k0+1] : WhhE1[row*64 + (k0+1-128)];
        w1[g][m] = mkh2(lo,hi);
      }
    }
    // e2: wave 1 (tid 64..127). unit j2 in [0,16), slice q2. K=96 {h1:64,h2:16,pad:16}
    const bool e2act = (tid >= 64 && tid < 128);
    const int q2 = tid & 3, j2 = (tid - 64) >> 2;
    half2v w2[4][12];
    float bias2[4] = {0.f,0.f,0.f,0.f};
    if (e2act){
#pragma unroll
      for (int g=0; g<4; ++g){
        const int row = g*16 + j2;
        bias2[g] = (q2==0) ? (bihE2[row]+bhhE2[row]) : 0.0f;
#pragma unroll
        for (int m=0;m<12;++m){
          const int k0 = 24*q2 + 2*m;
          float lo = 0.0f, hi = 0.0f;
          if (k0 < 64)        lo = WihE2[row*64+k0];
          else if (k0 < 80)   lo = WhhE2[row*16 + (k0-64)];
          if (k0+1 < 64)      hi = WihE2[row*64+k0+1];
          else if (k0+1 < 80) hi = WhhE2[row*16 + (k0+1-64)];
          w2[g][m] = mkh2(lo,hi);
        }
      }
    }
    // x staging: lanes 0..63 (also run e1), depth-2 register prefetch
    const bool xact = (tid < 64);
    const float* xrow = x + (size_t)b * (TT*128);
    float2 xa, xb;
    if (xact){
      float2 v0 = *(const float2*)(xrow + 2*tid);
      vhE[tid] = packh2(v0.x, v0.y);              // x(0) -> parity 0
      xa = *(const float2*)(xrow + 128 + 2*tid);
      xb = *(const float2*)(xrow + 256 + 2*tid);
    }
    if (tid >= 128 && tid < 160) vhE[64 + (tid-128)] = 0u;  // h1(-1)=0 (parity 0)
    if (tid >= 160 && tid < 256) e2op[tid-160] = 0u;        // h2(-1)+pads=0 (both par.)
    float c1 = 0.0f, c2 = 0.0f;
    __syncthreads();

    for (int t = 0; t <= TT; ++t){
      const int cur = t & 1, nxt = cur ^ 1;
      if (t < TT && xact){                        // stage x(t+1); refill depth-2
        vhE[nxt*96 + tid] = packh2(xa.x, xa.y);
        xa = xb;
        const int t3 = (t+3 < TT) ? (t+3) : (TT-1);
        xb = *(const float2*)(xrow + (size_t)t3*128 + 2*tid);
      }
      if (t < TT){                                // e1 step t
        float a0=bias1[0], a1=bias1[1], a2=bias1[2], a3=bias1[3];
        const uint4* vp = (const uint4*)(vhE + cur*96 + o*12);
#pragma unroll
        for (int r=0;r<3;++r){
          const uint4 u = vp[r];
          const half2v o0=ash2(u.x), o1=ash2(u.y), o2=ash2(u.z), o3=ash2(u.w);
          a0=dot2(w1[0][4*r+0],o0,a0); a1=dot2(w1[1][4*r+0],o0,a1);
          a2=dot2(w1[2][4*r+0],o0,a2); a3=dot2(w1[3][4*r+0],o0,a3);
          a0=dot2(w1[0][4*r+1],o1,a0); a1=dot2(w1[1][4*r+1],o1,a1);
          a2=dot2(w1[2][4*r+1],o1,a2); a3=dot2(w1[3][4*r+1],o1,a3);
          a0=dot2(w1[0][4*r+2],o2,a0); a1=dot2(w1[1][4*r+2],o2,a1);
          a2=dot2(w1[2][4*r+2],o2,a2); a3=dot2(w1[3][4*r+2],o2,a3);
          a0=dot2(w1[0][4*r+3],o3,a0); a1=dot2(w1[1][4*r+3],o3,a1);
          a2=dot2(w1[2][4*r+3],o3,a2); a3=dot2(w1[3][4*r+3],o3,a3);
        }
        a0=hsum8(a0); a1=hsum8(a1); a2=hsum8(a2); a3=hsum8(a3);
        const float h = lstm_update(o & 3, a0, a1, a2, a3, c1);
        if (o == 0){
          ((_Float16*)(vhE + nxt*96))[128 + j] = (_Float16)h;
          ((_Float16*)(e2op + cur*48))[j]      = (_Float16)fmaxf(h, 0.0f);
        }
      }
      if (t >= 1 && e2act){                       // e2 step t2 = t-1
        const int t2 = t-1, cp = t2 & 1, np = cp ^ 1;
        float a0=bias2[0], a1=bias2[1], a2=bias2[2], a3=bias2[3];
        const uint4* vp = (const uint4*)(e2op + cp*48 + q2*12);
#pragma unroll
        for (int r=0;r<3;++r){
          const uint4 u = vp[r];
          const half2v o0=ash2(u.x), o1=ash2(u.y), o2=ash2(u.z), o3=ash2(u.w);
          a0=dot2(w2[0][4*r+0],o0,a0); a1=dot2(w2[1][4*r+0],o0,a1);
          a2=dot2(w2[2][4*r+0],o0,a2); a3=dot2(w2[3][4*r+0],o0,a3);
          a0=dot2(w2[0][4*r+1],o1,a0); a1=dot2(w2[1][4*r+1],o1,a1);
          a2=dot2(w2[2][4*r+1],o1,a2); a3=dot2(w2[3][4*r+1],o1,a3);
          a0=dot2(w2[0][4*r+2],o2,a0); a1=dot2(w2[1][4*r+2],o2,a1);
          a2=dot2(w2[2][4*r+2],o2,a2); a3=dot2(w2[3][4*r+2],o2,a3);
          a0=dot2(w2[0][4*r+3],o3,a0); a1=dot2(w2[1][4*r+3],o3,a1);
          a2=dot2(w2[2][4*r+3],o3,a2); a3=dot2(w2[3][4*r+3],o3,a3);
        }
        a0=qsum2(qsum1(a0)); a1=qsum2(qsum1(a1));
        a2=qsum2(qsum1(a2)); a3=qsum2(qsum1(a3));
        const float h = lstm_update(q2, a0, a1, a2, a3, c2);
        if (q2 == 0){
          ((_Float16*)(e2op + np*48))[64 + j2] = (_Float16)h;
          if (t2 == TT-1) latF[j2] = fmaxf(h, 0.0f);
        }
      }
      __syncthreads();
    }
  }
  __syncthreads();
  asm volatile("" ::: "memory");   // e-loop weights die here

  //================= D-LOOP: d2 || d1(lag-1 lead, LDS weights) =================
  {
    // Fill wD1L: 8192 dw, 16 per thread. idx -> (r, l, d); lane l=(qd=l&3, jd=l>>2),
    // gate g=r>>1, lane-dword m=(r&1)*4+d, f16 k0 = qd*16 + 2m within K=64.
#pragma unroll
    for (int i=0;i<16;++i){
      const int idx = i*512 + tid;
      const int r = idx >> 10, rem = idx & 1023, l = rem >> 2, d = rem & 3;
      const int jd = l >> 2, qd = l & 3, g = r >> 1, m = ((r & 1) << 2) + d;
      const int row = g*64 + jd, k0 = qd*16 + 2*m;
      wD1L[idx] = packh2(WhhD1[row*64+k0], WhhD1[row*64+k0+1]);
    }

    const int qd = tid & 3, jd = tid >> 2;        // d2: unit jd in [0,128)
    half2v wD2[4][24];
    float biasD2[4];
#pragma unroll
    for (int g=0; g<4; ++g){
      const int row = g*128 + jd;
      biasD2[g] = (qd==0)? (bihD2[row]+bhhD2[row]) : 0.0f;
#pragma unroll
      for (int m=0;m<24;++m){
        const int k0 = 48*qd + 2*m;               // concat {x:64, h:128}
        const float lo = (k0   < 64)? WihD2[row*64+k0]   : WhhD2[row*128+(k0-64)];
        const float hi = (k0+1 < 64)? WihD2[row*64+k0+1] : WhhD2[row*128+(k0+1-64)];
        wD2[g][m] = mkh2(lo,hi);
      }
    }
    // d1: lanes<256. unit = tid>>2 in [0,64), slice = tid&3. proj from latent.
    const bool d1act = (tid < 256);
    float projD1[4] = {0.f,0.f,0.f,0.f};
    if (d1act && qd == 0){
#pragma unroll
      for (int g=0; g<4; ++g){
        const int row = g*64 + jd;
        float a = bihD1[row]+bhhD1[row];
#pragma unroll
        for (int i=0;i<16;++i) a = fmaf(WihD1[row*16+i], latF[i], a);
        projD1[g] = a;
      }
    }
    if (tid < 64)                dop[32 + tid] = 0u;   // hd2(-1)=0 (parity 0)
    if (tid >= 64 && tid < 96)   vhD1[tid-64] = 0u;    // hd1(-1)=0 (parity 0)
    float cd1 = 0.0f, cd2 = 0.0f;
    float* orow = out + (size_t)b * (TT*128);
    __syncthreads();

    for (int t = 0; t <= TT; ++t){
      const int cur = t & 1;
      // ----- d1 step t (lanes<256, leads d2 by 1; weights from LDS)
      if (t < TT && d1act){
        const int nxt = cur ^ 1;
        const uint4* ov = (const uint4*)(vhD1 + cur*32 + qd*8);
        const uint4 o01 = ov[0], o23 = ov[1];
        float a0=projD1[0], a1=projD1[1], a2=projD1[2], a3=projD1[3];
        {
          const uint4 wA = *(const uint4*)(wD1L + 0*1024 + tid*4);
          const uint4 wB = *(const uint4*)(wD1L + 1*1024 + tid*4);
          a0=dot2(ash2(wA.x),ash2(o01.x),a0); a0=dot2(ash2(wA.y),ash2(o01.y),a0);
          a0=dot2(ash2(wA.z),ash2(o01.z),a0); a0=dot2(ash2(wA.w),ash2(o01.w),a0);
          a0=dot2(ash2(wB.x),ash2(o23.x),a0); a0=dot2(ash2(wB.y),ash2(o23.y),a0);
          a0=dot2(ash2(wB.z),ash2(o23.z),a0); a0=dot2(ash2(wB.w),ash2(o23.w),a0);
        }
        {
          const uint4 wA = *(const uint4*)(wD1L + 2*1024 + tid*4);
          const uint4 wB = *(const uint4*)(wD1L + 3*1024 + tid*4);
          a1=dot2(ash2(wA.x),ash2(o01.x),a1); a1=dot2(ash2(wA.y),ash2(o01.y),a1);
          a1=dot2(ash2(wA.z),ash2(o01.z),a1); a1=dot2(ash2(wA.w),ash2(o01.w),a1);
          a1=dot2(ash2(wB.x),ash2(o23.x),a1); a1=dot2(ash2(wB.y),ash2(o23.y),a1);
          a1=dot2(ash2(wB.z),ash2(o23.z),a1); a1=dot2(ash2(wB.w),ash2(o23.w),a1);
        }
        {
          const uint4 wA = *(const uint4*)(wD1L + 4*1024 + tid*4);
          const uint4 wB = *(const uint4*)(wD1L + 5*1024 + tid*4);
          a2=dot2(ash2(wA.x),ash2(o01.x),a2); a2=dot2(ash2(wA.y),ash2(o01.y),a2);
          a2=dot2(ash2(wA.z),ash2(o01.z),a2); a2=dot2(ash2(wA.w),ash2(o01.w),a2);
          a2=dot2(ash2(wB.x),ash2(o23.x),a2); a2=dot2(ash2(wB.y),ash2(o23.y),a2);
          a2=dot2(ash2(wB.z),ash2(o23.z),a2); a2=dot2(ash2(wB.w),ash2(o23.w),a2);
        }
        {
          const uint4 wA = *(const uint4*)(wD1L + 6*1024 + tid*4);
          const uint4 wB = *(const uint4*)(wD1L + 7*1024 + tid*4);
          a3=dot2(ash2(wA.x),ash2(o01.x),a3); a3=dot2(ash2(wA.y),ash2(o01.y),a3);
          a3=dot2(ash2(wA.z),ash2(o01.z),a3); a3=dot2(ash2(wA.w),ash2(o01.w),a3);
          a3=dot2(ash2(wB.x),ash2(o23.x),a3); a3=dot2(ash2(wB.y),ash2(o23.y),a3);
          a3=dot2(ash2(wB.z),ash2(o23.z),a3); a3=dot2(ash2(wB.w),ash2(o23.w),a3);
        }
        a0=qsum2(qsum1(a0)); a1=qsum2(qsum1(a1));
        a2=qsum2(qsum1(a2)); a3=qsum2(qsum1(a3));
        const float h = lstm_update(qd, a0, a1, a2, a3, cd1);
        if (qd==0){
          ((_Float16*)(vhD1 + nxt*32))[jd] = (_Float16)h;
          ((_Float16*)(dop + cur*96))[jd]  = (_Float16)fmaxf(h,0.0f);
        }
      }
      // ----- d2 step t2 = t-1 (all lanes)
      if (t >= 1){
        const int t2 = t-1, c2p = t2 & 1, n2p = c2p ^ 1;
        float a0=biasD2[0], a1=biasD2[1], a2=biasD2[2], a3=biasD2[3];
        const uint4* vp = (const uint4*)(dop + c2p*96 + qd*24);
#pragma unroll
        for (int r=0;r<6;++r){
          const uint4 u = vp[r];
          const half2v o0=ash2(u.x),o1=ash2(u.y),o2=ash2(u.z),o3=ash2(u.w);
          a0=dot2(wD2[0][4*r+0],o0,a0); a1=dot2(wD2[1][4*r+0],o0,a1);
          a2=dot2(wD2[2][4*r+0],o0,a2); a3=dot2(wD2[3][4*r+0],o0,a3);
          a0=dot2(wD2[0][4*r+1],o1,a0); a1=dot2(wD2[1][4*r+1],o1,a1);
          a2=dot2(wD2[2][4*r+1],o1,a2); a3=dot2(wD2[3][4*r+1],o1,a3);
          a0=dot2(wD2[0][4*r+2],o2,a0); a1=dot2(wD2[1][4*r+2],o2,a1);
          a2=dot2(wD2[2][4*r+2],o2,a2); a3=dot2(wD2[3][4*r+2],o2,a3);
          a0=dot2(wD2[0][4*r+3],o3,a0); a1=dot2(wD2[1][4*r+3],o3,a1);
          a2=dot2(wD2[2][4*r+3],o3,a2); a3=dot2(wD2[3][4*r+3],o3,a3);
        }
        a0=qsum2(qsum1(a0)); a1=qsum2(qsum1(a1));
        a2=qsum2(qsum1(a2)); a3=qsum2(qsum1(a3));
        const float h = lstm_update(qd, a0, a1, a2, a3, cd2);
        if (qd==0){
          ((_Float16*)(dop + n2p*96))[64 + jd] = (_Float16)h;
          orow[(size_t)t2*128 + jd] = h;
        }
      }
      __syncthreads();
    }
  }
}

extern "C" void kernel_launch(void* const* d_in, const int* in_sizes, int n_in,
                              void* d_out, int out_size, void* d_ws, size_t ws_size,
                              hipStream_t stream) {
  const float* x      = (const float*)d_in[0];
  const float* WihE1  = (const float*)d_in[1];
  const float* WhhE1  = (const float*)d_in[2];
  const float* bihE1  = (const float*)d_in[3];
  const float* bhhE1  = (const float*)d_in[4];
  const float* WihE2  = (const float*)d_in[5];
  const float* WhhE2  = (const float*)d_in[6];
  const float* bihE2  = (const float*)d_in[7];
  const float* bhhE2  = (const float*)d_in[8];
  const float* WihD1  = (const float*)d_in[9];
  const float* WhhD1  = (const float*)d_in[10];
  const float* bihD1  = (const float*)d_in[11];
  const float* bhhD1  = (const float*)d_in[12];
  const float* WihD2  = (const float*)d_in[13];
  const float* WhhD2  = (const float*)d_in[14];
  const float* bihD2  = (const float*)d_in[15];
  const float* bhhD2  = (const float*)d_in[16];
  float* out = (float*)d_out;

  k_fused<<<BB, 512, 0, stream>>>(x,
      WihE1, WhhE1, bihE1, bhhE1,
      WihE2, WhhE2, bihE2, bhhE2,
      WihD1, WhhD1, bihD1, bhhD1,
      WihD2, WhhD2, bihD2, bhhD2,
      out);
}